// Round 7
// baseline (330.100 us; speedup 1.0000x reference)
//
#include <hip/hip_runtime.h>
#include <math.h>

#define B_    16
#define C_    256
#define NPIX  4096      // H*W
#define K_    4
#define HID_  512
#define ITERS_ 3
#define NROWS (B_*NPIX) // 65536

typedef __attribute__((ext_vector_type(8))) short bf16x8;
typedef __attribute__((ext_vector_type(4))) float f32x4;

__device__ __forceinline__ float gelu_f(float x) {
    return 0.5f * x * (1.0f + erff(x * 0.70710678118654752f));
}

__device__ __forceinline__ unsigned short f2bf(float x) {
    union { float f; unsigned u; } v; v.f = x;
    unsigned r = v.u + 0x7fffu + ((v.u >> 16) & 1u);   // round-nearest-even
    return (unsigned short)(r >> 16);
}
__device__ __forceinline__ float bflo(unsigned u) {
    union { unsigned u; float f; } v; v.u = u << 16; return v.f;
}
__device__ __forceinline__ float bfhi(unsigned u) {
    union { unsigned u; float f; } v; v.u = u & 0xffff0000u; return v.f;
}
__device__ __forceinline__ float4 shfl_xor4(float4 v, int m) {
    v.x = __shfl_xor(v.x, m); v.y = __shfl_xor(v.y, m);
    v.z = __shfl_xor(v.z, m); v.w = __shfl_xor(v.w, m);
    return v;
}
__device__ __forceinline__ void fma4(float4& a, const float4 w, const float4 s) {
    a.x = fmaf(w.x, s.x, a.x); a.y = fmaf(w.y, s.y, a.y);
    a.z = fmaf(w.z, s.z, a.z); a.w = fmaf(w.w, s.w, a.w);
}
__device__ __forceinline__ float hsum4(const float4 a) {
    return (a.x + a.y) + (a.z + a.w);
}

__device__ __forceinline__ void async_load16(const void* g, void* l) {
    __builtin_amdgcn_global_load_lds(
        (const __attribute__((address_space(1))) unsigned int*)g,
        (__attribute__((address_space(3))) unsigned int*)l, 16, 0, 0);
}

// 1024-thread block, reduce 256-entry red1/red2 arrays (writers stored before call)
__device__ __forceinline__ void reduce256_in1024(float* red1, float* red2, int tid,
                                                 float& o1, float& o2) {
    __syncthreads();
    for (int s = 128; s > 0; s >>= 1) {
        if (tid < s) { red1[tid] += red1[tid + s]; red2[tid] += red2[tid + s]; }
        __syncthreads();
    }
    o1 = red1[0]; o2 = red2[0];
    __syncthreads();
}

// ---------------- prep: bf16 kv weights + float4-packed slot weights ----------------
__global__ void prep_kernel(const float* __restrict__ Wk, const float* __restrict__ Wv,
                            const float* __restrict__ Wq, const float* __restrict__ Wu,
                            const float* __restrict__ W1, const float* __restrict__ W2,
                            const float* __restrict__ We1,
                            unsigned short* __restrict__ Wtb, float4* __restrict__ Wq4,
                            float4* __restrict__ Wu4, float4* __restrict__ W14,
                            float4* __restrict__ W24, float4* __restrict__ We14) {
    int t = blockIdx.x * 256 + threadIdx.x;        // 0..253951
    if (t < 131072) {
        int d = t >> 8, c = t & 255;
        float v = (d < 256) ? Wk[d * 256 + c] : Wv[(d - 256) * 256 + c];
        Wtb[t] = f2bf(v);
    } else {
        int i = t - 131072;                        // float4 index
        if (i < 16384) {                           // Wq4[c4][d]
            int c4 = i >> 8, d = i & 255;
            Wq4[i] = *(const float4*)&Wq[d * 256 + c4 * 4];
        } else if (i < 49152) {                    // Wu4[c4][d]
            int i2 = i - 16384; int c4 = i2 >> 8, d = i2 & 255;
            Wu4[i2] = *(const float4*)&Wu[d * 512 + c4 * 4];
        } else if (i < 81920) {                    // W14[c4][h]
            int i2 = i - 49152; int c4 = i2 >> 9, h = i2 & 511;
            W14[i2] = *(const float4*)&W1[h * 256 + c4 * 4];
        } else if (i < 114688) {                   // W24[h4][d]
            int i2 = i - 81920; int h4 = i2 >> 8, d = i2 & 255;
            W24[i2] = *(const float4*)&W2[d * 512 + h4 * 4];
        } else {                                   // We14[c4][e]
            int i2 = i - 114688; int c4 = i2 >> 7, e = i2 & 127;
            We14[i2] = *(const float4*)&We1[e * 256 + c4 * 4];
        }
    }
}

// ---------------- fused LN(+stats) + transpose + bf16 convert, single x pass ----------------
__global__ __launch_bounds__(256) void xn_fused_kernel(
    const float* __restrict__ x, const float* __restrict__ g, const float* __restrict__ bta,
    unsigned short* __restrict__ xnb) {
    __shared__ float tile[256][65];
    __shared__ float sg[256], sb[256];
    __shared__ float red1[256], red2[256];
    __shared__ float smean[64], srstd[64];
    const int tid = threadIdx.x;
    const int nt = blockIdx.x << 6, b = blockIdx.y;

    sg[tid] = g[tid]; sb[tid] = bta[tid];
    #pragma unroll
    for (int r = 0; r < 64; ++r) {
        int idx = tid + (r << 8);
        int c_l = idx >> 6, n_l = idx & 63;
        tile[c_l][n_l] = x[(size_t)(b * C_ + c_l) * NPIX + nt + n_l];
    }
    __syncthreads();
    {
        int cq = tid >> 6, n_l = tid & 63;
        float s = 0.f, s2 = 0.f;
        #pragma unroll 8
        for (int c = cq * 64; c < cq * 64 + 64; ++c) {
            float v = tile[c][n_l];
            s += v; s2 += v * v;
        }
        red1[tid] = s; red2[tid] = s2;
    }
    __syncthreads();
    if (tid < 64) {
        float s  = red1[tid] + red1[tid + 64] + red1[tid + 128] + red1[tid + 192];
        float s2 = red2[tid] + red2[tid + 64] + red2[tid + 128] + red2[tid + 192];
        float m = s * (1.0f / C_);
        smean[tid] = m;
        srstd[tid] = rsqrtf(s2 * (1.0f / C_) - m * m + 1e-5f);
    }
    __syncthreads();
    #pragma unroll
    for (int r = 0; r < 32; ++r) {
        int idx = tid + (r << 8);
        int n_l = idx >> 7, cp = idx & 127;
        int c0 = cp << 1;
        float mn = smean[n_l], rs = srstd[n_l];
        float v0 = (tile[c0][n_l] - mn) * rs * sg[c0] + sb[c0];
        float v1 = (tile[c0 + 1][n_l] - mn) * rs * sg[c0 + 1] + sb[c0 + 1];
        ushort2 o; o.x = f2bf(v0); o.y = f2bf(v1);
        *reinterpret_cast<ushort2*>(&xnb[((size_t)(b * NPIX + nt + n_l)) * C_ + c0]) = o;
    }
}

// ---------------- bf16 MFMA k/v projection GEMM ----------------
// BK=64, frag-linear LDS layout (staging chunk order == MFMA operand order):
// chunk L of a 16x32 frag-block holds global row m=L&15, k-shorts (L>>4)*8..+7.
// Both global_load_lds (base+lane*16) and ds_read_b128 (base+lane*16) are linear
// -> zero bank conflicts. Epilogue Cs unioned over As/Bs: LDS 32KB -> 5 blocks/CU.
__global__ __launch_bounds__(256) void kv_gemm_mfma(
    const unsigned short* __restrict__ xnb, const unsigned short* __restrict__ Wtb,
    const float* __restrict__ bk, const float* __restrict__ bv,
    unsigned short* __restrict__ kbuf, unsigned short* __restrict__ vbuf) {
    __shared__ __align__(16) char smem[32768];
    short* As = (short*)smem;                    // [8 subtiles][2 halves][512 shorts]
    short* Bs = As + 8192;
    unsigned short* Cs = (unsigned short*)smem;  // [64][136] epilogue, aliases As/Bs

    const int tid = threadIdx.x;
    const int wave = tid >> 6, lane = tid & 63;
    const int mtile = blockIdx.x << 7;
    const int ntile = blockIdx.y << 7;
    const int wr = wave >> 1, wc = wave & 1;

    f32x4 acc[4][4];
    #pragma unroll
    for (int i = 0; i < 4; ++i)
        #pragma unroll
        for (int j = 0; j < 4; ++j) acc[i][j] = (f32x4)0.f;

    const int srow = lane & 15;      // staged row within subtile
    const int skq  = lane >> 4;      // staged k-chunk 0..3

    for (int kc0 = 0; kc0 < C_; kc0 += 64) {
        #pragma unroll
        for (int j = 0; j < 2; ++j) {            // k-half of BK=64
            #pragma unroll
            for (int s = 0; s < 2; ++s) {
                int st = (wave << 1) + s;        // subtile 0..7 (16 rows each)
                int gk = kc0 + (((j << 2) + skq) << 3);
                async_load16(&xnb[(size_t)(mtile + (st << 4) + srow) * C_ + gk],
                             &As[(st << 10) + (j << 9)]);
                async_load16(&Wtb[(size_t)(ntile + (st << 4) + srow) * C_ + gk],
                             &Bs[(st << 10) + (j << 9)]);
            }
        }
        __syncthreads();
        #pragma unroll
        for (int h = 0; h < 2; ++h) {
            bf16x8 af[4], bfr[4];
            #pragma unroll
            for (int mi = 0; mi < 4; ++mi)
                af[mi] = *reinterpret_cast<const bf16x8*>(
                    &As[(((wr << 2) + mi) << 10) + (h << 9) + (lane << 3)]);
            #pragma unroll
            for (int ni = 0; ni < 4; ++ni)
                bfr[ni] = *reinterpret_cast<const bf16x8*>(
                    &Bs[(((wc << 2) + ni) << 10) + (h << 9) + (lane << 3)]);
            #pragma unroll
            for (int mi = 0; mi < 4; ++mi)
                #pragma unroll
                for (int ni = 0; ni < 4; ++ni)
                    acc[mi][ni] = __builtin_amdgcn_mfma_f32_16x16x32_bf16(
                        af[mi], bfr[ni], acc[mi][ni], 0, 0, 0);
        }
        __syncthreads();
    }

    // two-pass epilogue through unioned Cs (64 rows x 128 cols, stride 136)
    unsigned short* obuf = (blockIdx.y < 2) ? kbuf : vbuf;
    const int cb = (blockIdx.y & 1) << 7;
    #pragma unroll
    for (int p = 0; p < 2; ++p) {
        if (wr == p) {
            #pragma unroll
            for (int ni = 0; ni < 4; ++ni) {
                int col_l = (wc << 6) + (ni << 4) + (lane & 15);
                int gcol = ntile + col_l;
                float bias = (gcol < 256) ? bk[gcol] : bv[gcol - 256];
                #pragma unroll
                for (int mi = 0; mi < 4; ++mi) {
                    int row0 = (mi << 4) + ((lane >> 4) << 2);
                    #pragma unroll
                    for (int r = 0; r < 4; ++r)
                        Cs[(row0 + r) * 136 + col_l] = f2bf(acc[mi][ni][r] + bias);
                }
            }
        }
        __syncthreads();
        #pragma unroll
        for (int rep = 0; rep < 4; ++rep) {
            int idx = (rep << 8) + tid;          // 0..1023 16B-chunks
            int row = idx >> 4;
            int ch = (idx & 15) << 3;            // shorts
            uint4 dd = *reinterpret_cast<const uint4*>(&Cs[row * 136 + ch]);
            *reinterpret_cast<uint4*>(
                &obuf[(size_t)(mtile + (p << 6) + row) * C_ + cb + ch]) = dd;
        }
        __syncthreads();
    }
}

// ---------------- slot kernels: 1024 threads, K split 4 ways (q = tid>>8) ----------------

// LN(v over d for q==0) + q-projection; all 1024 threads participate
__device__ __forceinline__ void ln_q_1024(float v, int tid, int d, int q, int r,
                                          const float* __restrict__ g_sl,
                                          const float* __restrict__ b_sl,
                                          const float4* __restrict__ Wq4,
                                          const float* __restrict__ bq,
                                          float* __restrict__ qbuf,
                                          float* snorm, float* pq,
                                          float* redA, float* redB) {
    if (q == 0) { redA[d] = v; redB[d] = v * v; }
    float sm, s2;
    reduce256_in1024(redA, redB, tid, sm, s2);
    if (q == 0) {
        float m = sm * (1.f / C_);
        float rs = rsqrtf(s2 * (1.f / C_) - m * m + 1e-5f);
        snorm[d] = (v - m) * rs * g_sl[d] + b_sl[d];
    }
    __syncthreads();
    const float4* sn4 = (const float4*)snorm;
    float4 a0 = {0,0,0,0}, a1 = {0,0,0,0};
    int c4b = q << 4;
    #pragma unroll
    for (int i = 0; i < 16; i += 2) {
        fma4(a0, Wq4[(c4b + i) * 256 + d], sn4[c4b + i]);
        fma4(a1, Wq4[(c4b + i + 1) * 256 + d], sn4[c4b + i + 1]);
    }
    pq[q * 256 + d] = hsum4(a0) + hsum4(a1);
    __syncthreads();
    if (q == 0)
        qbuf[r * C_ + d] = pq[d] + pq[256 + d] + pq[512 + d] + pq[768 + d] + bq[d];
}

__global__ __launch_bounds__(1024) void slot_init_q_kernel(
    const float* __restrict__ noise, const float* __restrict__ mu,
    const float* __restrict__ log_sigma,
    const float* __restrict__ g_sl, const float* __restrict__ b_sl,
    const float4* __restrict__ Wq4, const float* __restrict__ bq,
    float* __restrict__ slots, float* __restrict__ qbuf) {
    __shared__ __align__(16) float snorm[256];
    __shared__ float pq[1024];
    __shared__ float redA[256], redB[256];
    int tid = threadIdx.x;
    int d = tid & 255, q = tid >> 8;
    int r = blockIdx.x;
    float v = 0.f;
    if (q == 0) {
        v = mu[d] + expf(log_sigma[d]) * noise[r * C_ + d];
        slots[r * C_ + d] = v;
    }
    ln_q_1024(v, tid, d, q, r, g_sl, b_sl, Wq4, bq, qbuf, snorm, pq, redA, redB);
}

// slot update core; returns ov (valid for q==0 threads)
__device__ __forceinline__ float slot_update_body(
    int tid, int d, int q, int r, const float* __restrict__ slots,
    const float* __restrict__ partials, const float* __restrict__ asump,
    const float4* __restrict__ Wu4, const float* __restrict__ bu,
    const float* __restrict__ g_mlp, const float* __restrict__ b_mlp,
    const float4* __restrict__ W14, const float* __restrict__ b1,
    const float4* __restrict__ W24, const float* __restrict__ b2,
    float* comb, float* pq, float* mrow, float* hrow,
    float* redA, float* redB, float* s_denom) {
    int b = r >> 2, kk = r & 3;
    // phase 0: partials reduce (16 chunks per quarter)
    {
        const float* pbase = partials + (size_t)b * 65536 + kk * 256 + d;
        float u0 = 0.f, u1 = 0.f, u2 = 0.f, u3 = 0.f;
        int j0 = q << 4;
        #pragma unroll
        for (int j = 0; j < 16; j += 4) {
            u0 += pbase[(j0 + j + 0) * 1024];
            u1 += pbase[(j0 + j + 1) * 1024];
            u2 += pbase[(j0 + j + 2) * 1024];
            u3 += pbase[(j0 + j + 3) * 1024];
        }
        pq[q * 256 + d] = (u0 + u1) + (u2 + u3);
    }
    if (tid < 64) {
        float dv = asump[(b * 64 + tid) * 4 + kk];
        #pragma unroll
        for (int m = 1; m <= 32; m <<= 1) dv += __shfl_xor(dv, m);
        if (tid == 0) *s_denom = dv + 1e-8f;
    }
    float prev = 0.f;
    if (q == 0) prev = slots[r * C_ + d];
    __syncthreads();
    if (q == 0) {
        comb[d] = prev;
        comb[256 + d] = (pq[d] + pq[256 + d] + pq[512 + d] + pq[768 + d]) / *s_denom;
    }
    __syncthreads();
    // phase 1: Wu (K=512), quarter = 32 c4
    const float4* cb4 = (const float4*)comb;
    {
        float4 a0 = {0,0,0,0}, a1 = {0,0,0,0}, a2 = {0,0,0,0}, a3 = {0,0,0,0};
        int c4b = q << 5;
        #pragma unroll
        for (int i = 0; i < 32; i += 4) {
            float4 w0 = Wu4[(c4b + i + 0) * 256 + d];
            float4 w1 = Wu4[(c4b + i + 1) * 256 + d];
            float4 w2 = Wu4[(c4b + i + 2) * 256 + d];
            float4 w3 = Wu4[(c4b + i + 3) * 256 + d];
            fma4(a0, w0, cb4[c4b + i + 0]); fma4(a1, w1, cb4[c4b + i + 1]);
            fma4(a2, w2, cb4[c4b + i + 2]); fma4(a3, w3, cb4[c4b + i + 3]);
        }
        pq[q * 256 + d] = (hsum4(a0) + hsum4(a1)) + (hsum4(a2) + hsum4(a3));
    }
    __syncthreads();
    float nv = 0.f;
    if (q == 0) {
        nv = pq[d] + pq[256 + d] + pq[512 + d] + pq[768 + d] + bu[d] + prev;
        redA[d] = nv; redB[d] = nv * nv;
    }
    float sm, s2;
    reduce256_in1024(redA, redB, tid, sm, s2);
    if (q == 0) {
        float m = sm * (1.f / C_);
        float rs = rsqrtf(s2 * (1.f / C_) - m * m + 1e-5f);
        mrow[d] = (nv - m) * rs * g_mlp[d] + b_mlp[d];
    }
    __syncthreads();
    // phase 2: W1 (K=256 -> 512 outputs), halves (h2 = tid>>9)
    const float4* m4 = (const float4*)mrow;
    {
        int j = tid & 511, h2 = tid >> 9;
        float4 a0 = {0,0,0,0}, a1 = {0,0,0,0};
        int c4b = h2 << 5;
        #pragma unroll
        for (int i = 0; i < 32; i += 2) {
            float4 w0 = W14[(c4b + i + 0) * 512 + j];
            float4 w1 = W14[(c4b + i + 1) * 512 + j];
            fma4(a0, w0, m4[c4b + i + 0]); fma4(a1, w1, m4[c4b + i + 1]);
        }
        pq[h2 * 512 + j] = hsum4(a0) + hsum4(a1);
    }
    __syncthreads();
    if (tid < 512) hrow[tid] = gelu_f(pq[tid] + pq[512 + tid] + b1[tid]);
    __syncthreads();
    // phase 3: W2 (K=512)
    const float4* h4 = (const float4*)hrow;
    {
        float4 a0 = {0,0,0,0}, a1 = {0,0,0,0}, a2 = {0,0,0,0}, a3 = {0,0,0,0};
        int h4b = q << 5;
        #pragma unroll
        for (int i = 0; i < 32; i += 4) {
            float4 w0 = W24[(h4b + i + 0) * 256 + d];
            float4 w1 = W24[(h4b + i + 1) * 256 + d];
            float4 w2 = W24[(h4b + i + 2) * 256 + d];
            float4 w3 = W24[(h4b + i + 3) * 256 + d];
            fma4(a0, w0, h4[h4b + i + 0]); fma4(a1, w1, h4[h4b + i + 1]);
            fma4(a2, w2, h4[h4b + i + 2]); fma4(a3, w3, h4[h4b + i + 3]);
        }
        pq[q * 256 + d] = (hsum4(a0) + hsum4(a1)) + (hsum4(a2) + hsum4(a3));
    }
    __syncthreads();
    float ov = 0.f;
    if (q == 0)
        ov = nv + pq[d] + pq[256 + d] + pq[512 + d] + pq[768 + d] + b2[d];
    return ov;
}

__global__ __launch_bounds__(1024) void slot_update_q_kernel(
    float* __restrict__ slots, const float* __restrict__ partials, const float* __restrict__ asump,
    const float4* __restrict__ Wu4, const float* __restrict__ bu,
    const float* __restrict__ g_mlp, const float* __restrict__ b_mlp,
    const float4* __restrict__ W14, const float* __restrict__ b1,
    const float4* __restrict__ W24, const float* __restrict__ b2,
    const float* __restrict__ g_sl, const float* __restrict__ b_sl,
    const float4* __restrict__ Wq4, const float* __restrict__ bq,
    float* __restrict__ qbuf) {
    __shared__ __align__(16) float comb[512];
    __shared__ __align__(16) float mrow[256];
    __shared__ __align__(16) float hrow[512];
    __shared__ float pq[1024];
    __shared__ float redA[256], redB[256];
    __shared__ float s_denom;
    int tid = threadIdx.x;
    int d = tid & 255, q = tid >> 8;
    int r = blockIdx.x;
    float ov = slot_update_body(tid, d, q, r, slots, partials, asump, Wu4, bu,
                                g_mlp, b_mlp, W14, b1, W24, b2,
                                comb, pq, mrow, hrow, redA, redB, &s_denom);
    if (q == 0) slots[r * C_ + d] = ov;
    __syncthreads();
    ln_q_1024(ov, tid, d, q, r, g_sl, b_sl, Wq4, bq, qbuf, mrow, pq, redA, redB);
}

__global__ __launch_bounds__(1024) void slot_update_final_kernel(
    float* __restrict__ slots, const float* __restrict__ partials, const float* __restrict__ asump,
    const float4* __restrict__ Wu4, const float* __restrict__ bu,
    const float* __restrict__ g_mlp, const float* __restrict__ b_mlp,
    const float4* __restrict__ W14, const float* __restrict__ b1,
    const float4* __restrict__ W24, const float* __restrict__ b2,
    const float4* __restrict__ We14, const float* __restrict__ be1,
    const float* __restrict__ We2, const float* __restrict__ be2,
    float* __restrict__ out) {
    __shared__ __align__(16) float comb[512];
    __shared__ __align__(16) float mrow[256];
    __shared__ __align__(16) float hrow[512];
    __shared__ float pq[1024];
    __shared__ float redA[256], redB[256];
    __shared__ float s_denom;
    __shared__ float erow[128];
    int tid = threadIdx.x;
    int d = tid & 255, q = tid >> 8;
    int r = blockIdx.x;
    float ov = slot_update_body(tid, d, q, r, slots, partials, asump, Wu4, bu,
                                g_mlp, b_mlp, W14, b1, W24, b2,
                                comb, pq, mrow, hrow, redA, redB, &s_denom);
    if (q == 0) {
        out[r * C_ + d] = ov;
        mrow[d] = ov;
    }
    __syncthreads();
    // We1: 128 outputs, 8-way K split (o8 = tid>>7, 8 c4 each)
    const float4* m4 = (const float4*)mrow;
    {
        int e = tid & 127, o8 = tid >> 7;
        float4 a0 = {0,0,0,0}, a1 = {0,0,0,0};
        int c4b = o8 << 3;
        #pragma unroll
        for (int i = 0; i < 8; i += 2) {
            fma4(a0, We14[(c4b + i) * 128 + e], m4[c4b + i]);
            fma4(a1, We14[(c4b + i + 1) * 128 + e], m4[c4b + i + 1]);
        }
        pq[o8 * 128 + e] = hsum4(a0) + hsum4(a1);
    }
    __syncthreads();
    if (tid < 128) {
        float s = 0.f;
        #pragma unroll
        for (int o = 0; o < 8; ++o) s += pq[o * 128 + tid];
        erow[tid] = gelu_f(s + be1[tid]);
    }
    __syncthreads();
    if (tid < 64) {
        float p = We2[tid] * erow[tid] + We2[tid + 64] * erow[tid + 64];
        #pragma unroll
        for (int m = 1; m <= 32; m <<= 1) p += __shfl_xor(p, m);
        if (tid == 0) out[B_ * K_ * C_ + r] = 1.0f / (1.0f + expf(-(p + be2[0])));
    }
}

// ---------------- fused attention (unchanged) ----------------
__global__ __launch_bounds__(256) void attn_fused_kernel(
    const float* __restrict__ qbuf, const unsigned short* __restrict__ kbuf,
    const unsigned short* __restrict__ vbuf,
    float* __restrict__ partials, float* __restrict__ asump) {
    __shared__ float4 qT[264];
    __shared__ float attns[K_][64];
    __shared__ float upd_s[K_][256];
    __shared__ float asw[4][4];

    const int tid = threadIdx.x;
    const int b = blockIdx.y;
    const int chunk = blockIdx.x;
    const int n0 = chunk << 6;
    const int wave = tid >> 6, lane = tid & 63;

    {
        int c = tid;
        float4 qv;
        qv.x = qbuf[b * 1024 + c];
        qv.y = qbuf[b * 1024 + 256 + c];
        qv.z = qbuf[b * 1024 + 512 + c];
        qv.w = qbuf[b * 1024 + 768 + c];
        qT[c + (c >> 5)] = qv;
    }
    __syncthreads();

    const int cpart = tid & 7;
    const int npair = tid >> 3;
    const int c0 = cpart << 5;
    float4 acc0 = {0.f, 0.f, 0.f, 0.f}, acc1 = {0.f, 0.f, 0.f, 0.f};
    const unsigned short* kbase = kbuf + ((size_t)b * NPIX + n0 + npair * 2) * C_ + c0;
    #pragma unroll
    for (int j = 0; j < 4; ++j) {
        uint4 k0 = *reinterpret_cast<const uint4*>(kbase + j * 8);
        uint4 k1 = *reinterpret_cast<const uint4*>(kbase + C_ + j * 8);
        const unsigned kw0[4] = {k0.x, k0.y, k0.z, k0.w};
        const unsigned kw1[4] = {k1.x, k1.y, k1.z, k1.w};
        #pragma unroll
        for (int jj = 0; jj < 4; ++jj) {
            int cidx = c0 + j * 8 + jj * 2 + cpart;
            float4 qa = qT[cidx];
            float4 qb = qT[cidx + 1];
            float f00 = bflo(kw0[jj]), f01 = bfhi(kw0[jj]);
            float f10 = bflo(kw1[jj]), f11 = bfhi(kw1[jj]);
            acc0.x += f00 * qa.x + f01 * qb.x;  acc0.y += f00 * qa.y + f01 * qb.y;
            acc0.z += f00 * qa.z + f01 * qb.z;  acc0.w += f00 * qa.w + f01 * qb.w;
            acc1.x += f10 * qa.x + f11 * qb.x;  acc1.y += f10 * qa.y + f11 * qb.y;
            acc1.z += f10 * qa.z + f11 * qb.z;  acc1.w += f10 * qa.w + f11 * qb.w;
        }
    }
    #pragma unroll
    for (int m = 1; m <= 4; m <<= 1) {
        acc0 = acc0 + shfl_xor4(acc0, m);
        acc1 = acc1 + shfl_xor4(acc1, m);
    }
    float4 w0, w1;
    {
        float4 l = acc0 * 0.0625f;
        float mx = fmaxf(fmaxf(l.x, l.y), fmaxf(l.z, l.w));
        w0.x = expf(l.x - mx); w0.y = expf(l.y - mx);
        w0.z = expf(l.z - mx); w0.w = expf(l.w - mx);
        float inv = 1.0f / (w0.x + w0.y + w0.z + w0.w);
        w0 = w0 * inv;
        l = acc1 * 0.0625f;
        mx = fmaxf(fmaxf(l.x, l.y), fmaxf(l.z, l.w));
        w1.x = expf(l.x - mx); w1.y = expf(l.y - mx);
        w1.z = expf(l.z - mx); w1.w = expf(l.w - mx);
        inv = 1.0f / (w1.x + w1.y + w1.z + w1.w);
        w1 = w1 * inv;
    }
    if (cpart == 0) {
        int n_l = npair * 2;
        attns[0][n_l] = w0.x; attns[1][n_l] = w0.y; attns[2][n_l] = w0.z; attns[3][n_l] = w0.w;
        attns[0][n_l + 1] = w1.x; attns[1][n_l + 1] = w1.y;
        attns[2][n_l + 1] = w1.z; attns[3][n_l + 1] = w1.w;
    }
    float4 ws = w0 + w1;
    #pragma unroll
    for (int m = 8; m <= 32; m <<= 1) ws = ws + shfl_xor4(ws, m);
    if (lane == 0) {
        asw[wave][0] = ws.x; asw[wave][1] = ws.y; asw[wave][2] = ws.z; asw[wave][3] = ws.w;
    }
    __syncthreads();
    if (tid < 4)
        asump[(b * 64 + chunk) * 4 + tid] =
            asw[0][tid] + asw[1][tid] + asw[2][tid] + asw[3][tid];

    const int h = wave >> 1;
    const int chalf = (wave & 1) << 7;
    const int c = chalf + lane * 2;
    float a0[K_] = {0.f, 0.f, 0.f, 0.f};
    float a1[K_] = {0.f, 0.f, 0.f, 0.f};
    const unsigned short* vbase = vbuf + ((size_t)b * NPIX + n0 + h * 32) * C_ + c;
    #pragma unroll 4
    for (int nn = 0; nn < 32; ++nn) {
        unsigned vv = *reinterpret_cast<const unsigned*>(vbase + (size_t)nn * C_);
        float v0 = bflo(vv), v1 = bfhi(vv);
        int n_l = h * 32 + nn;
        float q0 = attns[0][n_l], q1 = attns[1][n_l], q2 = attns[2][n_l], q3 = attns[3][n_l];
        a0[0] = fmaf(q0, v0, a0[0]); a1[0] = fmaf(q0, v1, a1[0]);
        a0[1] = fmaf(q1, v0, a0[1]); a1[1] = fmaf(q1, v1, a1[1]);
        a0[2] = fmaf(q2, v0, a0[2]); a1[2] = fmaf(q2, v1, a1[2]);
        a0[3] = fmaf(q3, v0, a0[3]); a1[3] = fmaf(q3, v1, a1[3]);
    }
    __syncthreads();
    if (h == 0) {
        #pragma unroll
        for (int k = 0; k < K_; ++k) { upd_s[k][c] = a0[k]; upd_s[k][c + 1] = a1[k]; }
    }
    __syncthreads();
    if (h == 1) {
        #pragma unroll
        for (int k = 0; k < K_; ++k) { upd_s[k][c] += a0[k]; upd_s[k][c + 1] += a1[k]; }
    }
    __syncthreads();
    float* pb = partials + (size_t)(b * 64 + chunk) * (K_ * 256);
    #pragma unroll
    for (int k = 0; k < K_; ++k) pb[k * 256 + tid] = upd_s[k][tid];
}

extern "C" void kernel_launch(void* const* d_in, const int* in_sizes, int n_in,
                              void* d_out, int out_size, void* d_ws, size_t ws_size,
                              hipStream_t stream) {
    (void)in_sizes; (void)n_in; (void)out_size; (void)ws_size;
    const float* x        = (const float*)d_in[0];
    const float* noise    = (const float*)d_in[1];
    const float* slot_mu  = (const float*)d_in[2];
    const float* slot_ls  = (const float*)d_in[3];
    const float* ln_in_g  = (const float*)d_in[4];
    const float* ln_in_b  = (const float*)d_in[5];
    const float* ln_sl_g  = (const float*)d_in[6];
    const float* ln_sl_b  = (const float*)d_in[7];
    const float* ln_mlp_g = (const float*)d_in[8];
    const float* ln_mlp_b = (const float*)d_in[9];
    const float* Wq = (const float*)d_in[10];
    const float* bq = (const float*)d_in[11];
    const float* Wk = (const float*)d_in[12];
    const float* bk = (const float*)d_in[13];
    const float* Wv = (const float*)d_in[14];
    const float* bv = (const float*)d_in[15];
    const float* Wu = (const float*)d_in[16];
    const float* bu = (const float*)d_in[17];
    const float* W1 = (const float*)d_in[18];
    const float* b1 = (const float*)d_in[19];
    const float* W2 = (const float*)d_in[20];
    const float* b2 = (const float*)d_in[21];
    const float* We1 = (const float*)d_in[22];
    const float* be1 = (const float*)d_in[23];
    const float* We2 = (const float*)d_in[24];
    const float* be2 = (const float*)d_in[25];
    float* out = (float*)d_out;

    char* ws = (char*)d_ws;
    unsigned short* kbuf = (unsigned short*)ws;
    unsigned short* vbuf = kbuf + (size_t)NROWS * C_;
    unsigned short* xnb  = vbuf + (size_t)NROWS * C_;
    unsigned short* Wtb  = xnb + (size_t)NROWS * C_;
    float4* Wq4  = (float4*)(Wtb + 512 * C_);
    float4* Wu4  = Wq4 + 16384;
    float4* W14  = Wu4 + 32768;
    float4* W24  = W14 + 32768;
    float4* We14 = W24 + 32768;
    float* slots = (float*)(We14 + 8192);
    float* qbuf  = slots + B_ * K_ * C_;
    float* partials = qbuf + B_ * K_ * C_;
    float* asump = partials + (size_t)B_ * 64 * K_ * 256;

    prep_kernel<<<992, 256, 0, stream>>>(Wk, Wv, Wq, Wu, W1, W2, We1,
                                         Wtb, Wq4, Wu4, W14, W24, We14);
    xn_fused_kernel<<<dim3(64, 16), 256, 0, stream>>>(x, ln_in_g, ln_in_b, xnb);
    slot_init_q_kernel<<<B_ * K_, 1024, 0, stream>>>(noise, slot_mu, slot_ls,
                                                     ln_sl_g, ln_sl_b, Wq4, bq, slots, qbuf);
    kv_gemm_mfma<<<dim3(512, 4), 256, 0, stream>>>(xnb, Wtb, bk, bv, kbuf, vbuf);
    for (int it = 0; it < ITERS_; ++it) {
        attn_fused_kernel<<<dim3(64, 16), 256, 0, stream>>>(qbuf, kbuf, vbuf, partials, asump);
        if (it < ITERS_ - 1) {
            slot_update_q_kernel<<<B_ * K_, 1024, 0, stream>>>(
                slots, partials, asump, Wu4, bu, ln_mlp_g, ln_mlp_b, W14, b1, W24, b2,
                ln_sl_g, ln_sl_b, Wq4, bq, qbuf);
        } else {
            slot_update_final_kernel<<<B_ * K_, 1024, 0, stream>>>(
                slots, partials, asump, Wu4, bu, ln_mlp_g, ln_mlp_b, W14, b1, W24, b2,
                We14, be1, We2, be2, out);
        }
    }
}

// Round 8
// 315.224 us; speedup vs baseline: 1.0472x; 1.0472x over previous
//
#include <hip/hip_runtime.h>
#include <math.h>

#define B_    16
#define C_    256
#define NPIX  4096      // H*W
#define K_    4
#define HID_  512
#define ITERS_ 3
#define NROWS (B_*NPIX) // 65536
#define EPS_  1e-8f

typedef __attribute__((ext_vector_type(8))) short bf16x8;
typedef __attribute__((ext_vector_type(4))) float f32x4;

__device__ __forceinline__ float gelu_f(float x) {
    return 0.5f * x * (1.0f + erff(x * 0.70710678118654752f));
}

__device__ __forceinline__ unsigned short f2bf(float x) {
    union { float f; unsigned u; } v; v.f = x;
    unsigned r = v.u + 0x7fffu + ((v.u >> 16) & 1u);   // round-nearest-even
    return (unsigned short)(r >> 16);
}
__device__ __forceinline__ float bflo(unsigned u) {
    union { unsigned u; float f; } v; v.u = u << 16; return v.f;
}
__device__ __forceinline__ float bfhi(unsigned u) {
    union { unsigned u; float f; } v; v.u = u & 0xffff0000u; return v.f;
}
__device__ __forceinline__ float4 shfl_xor4(float4 v, int m) {
    v.x = __shfl_xor(v.x, m); v.y = __shfl_xor(v.y, m);
    v.z = __shfl_xor(v.z, m); v.w = __shfl_xor(v.w, m);
    return v;
}
__device__ __forceinline__ void fma4(float4& a, const float4 w, const float4 s) {
    a.x = fmaf(w.x, s.x, a.x); a.y = fmaf(w.y, s.y, a.y);
    a.z = fmaf(w.z, s.z, a.z); a.w = fmaf(w.w, s.w, a.w);
}
__device__ __forceinline__ float hsum4(const float4 a) {
    return (a.x + a.y) + (a.z + a.w);
}

// 1024-thread block, reduce 256-entry red1/red2 arrays (writers stored before call)
__device__ __forceinline__ void reduce256_in1024(float* red1, float* red2, int tid,
                                                 float& o1, float& o2) {
    __syncthreads();
    for (int s = 128; s > 0; s >>= 1) {
        if (tid < s) { red1[tid] += red1[tid + s]; red2[tid] += red2[tid + s]; }
        __syncthreads();
    }
    o1 = red1[0]; o2 = red2[0];
    __syncthreads();
}

// ---------------- prep: float4-packed weights ----------------
// Wq4[c4][d]   = {Wq[d][4c4..]}      (16384)
// Wu4[c4][d]   = {Wu[d][4c4..]}      (32768)
// W14[c4][h]   = {W1[h][4c4..]}      (32768)
// W24[h4][d]   = {W2[d][4h4..]}      (32768)
// We14[c4][e]  = {We1[e][4c4..]}     (8192)
// Wkq4[d4][c]  = {Wk[4d4+j][c]}      (16384)  -- for qt = q . Wk
// Wv4[e4][d]   = {Wv[d][4e4..]}      (16384)  -- for updates = Wv . u'
__global__ void prep_kernel(const float* __restrict__ Wq, const float* __restrict__ Wu,
                            const float* __restrict__ W1, const float* __restrict__ W2,
                            const float* __restrict__ We1, const float* __restrict__ Wk,
                            const float* __restrict__ Wv,
                            float4* __restrict__ Wq4, float4* __restrict__ Wu4,
                            float4* __restrict__ W14, float4* __restrict__ W24,
                            float4* __restrict__ We14, float4* __restrict__ Wkq4,
                            float4* __restrict__ Wv4) {
    int i = blockIdx.x * 256 + threadIdx.x;        // float4 index, 0..155647
    if (i < 16384) {
        int c4 = i >> 8, d = i & 255;
        Wq4[i] = *(const float4*)&Wq[d * 256 + c4 * 4];
    } else if (i < 49152) {
        int j = i - 16384; int c4 = j >> 8, d = j & 255;
        Wu4[j] = *(const float4*)&Wu[d * 512 + c4 * 4];
    } else if (i < 81920) {
        int j = i - 49152; int c4 = j >> 9, h = j & 511;
        W14[j] = *(const float4*)&W1[h * 256 + c4 * 4];
    } else if (i < 114688) {
        int j = i - 81920; int h4 = j >> 8, d = j & 255;
        W24[j] = *(const float4*)&W2[d * 512 + h4 * 4];
    } else if (i < 122880) {
        int j = i - 114688; int c4 = j >> 7, e = j & 127;
        We14[j] = *(const float4*)&We1[e * 256 + c4 * 4];
    } else if (i < 139264) {
        int j = i - 122880; int d4 = j >> 8, c = j & 255;
        float4 o;
        o.x = Wk[(4 * d4 + 0) * 256 + c];
        o.y = Wk[(4 * d4 + 1) * 256 + c];
        o.z = Wk[(4 * d4 + 2) * 256 + c];
        o.w = Wk[(4 * d4 + 3) * 256 + c];
        Wkq4[j] = o;
    } else {
        int j = i - 139264; int e4 = j >> 8, d = j & 255;
        Wv4[j] = *(const float4*)&Wv[d * 256 + e4 * 4];
    }
}

// ---------------- fused LN(+stats) + transpose + bf16 convert, single x pass ----------------
__global__ __launch_bounds__(256) void xn_fused_kernel(
    const float* __restrict__ x, const float* __restrict__ g, const float* __restrict__ bta,
    unsigned short* __restrict__ xnb) {
    __shared__ float tile[256][65];
    __shared__ float sg[256], sb[256];
    __shared__ float red1[256], red2[256];
    __shared__ float smean[64], srstd[64];
    const int tid = threadIdx.x;
    const int nt = blockIdx.x << 6, b = blockIdx.y;

    sg[tid] = g[tid]; sb[tid] = bta[tid];
    #pragma unroll
    for (int r = 0; r < 64; ++r) {
        int idx = tid + (r << 8);
        int c_l = idx >> 6, n_l = idx & 63;
        tile[c_l][n_l] = x[(size_t)(b * C_ + c_l) * NPIX + nt + n_l];
    }
    __syncthreads();
    {
        int cq = tid >> 6, n_l = tid & 63;
        float s = 0.f, s2 = 0.f;
        #pragma unroll 8
        for (int c = cq * 64; c < cq * 64 + 64; ++c) {
            float v = tile[c][n_l];
            s += v; s2 += v * v;
        }
        red1[tid] = s; red2[tid] = s2;
    }
    __syncthreads();
    if (tid < 64) {
        float s  = red1[tid] + red1[tid + 64] + red1[tid + 128] + red1[tid + 192];
        float s2 = red2[tid] + red2[tid + 64] + red2[tid + 128] + red2[tid + 192];
        float m = s * (1.0f / C_);
        smean[tid] = m;
        srstd[tid] = rsqrtf(s2 * (1.0f / C_) - m * m + 1e-5f);
    }
    __syncthreads();
    #pragma unroll
    for (int r = 0; r < 32; ++r) {
        int idx = tid + (r << 8);
        int n_l = idx >> 7, cp = idx & 127;
        int c0 = cp << 1;
        float mn = smean[n_l], rs = srstd[n_l];
        float v0 = (tile[c0][n_l] - mn) * rs * sg[c0] + sb[c0];
        float v1 = (tile[c0 + 1][n_l] - mn) * rs * sg[c0 + 1] + sb[c0 + 1];
        ushort2 o; o.x = f2bf(v0); o.y = f2bf(v1);
        *reinterpret_cast<ushort2*>(&xnb[((size_t)(b * NPIX + nt + n_l)) * C_ + c0]) = o;
    }
}

// ---------------- slot kernels: 1024 threads, K split 4 ways (q = tid>>8) ----------------

// LN + q-projection + qt = q.Wk + qoff = q.bk
__device__ __forceinline__ void ln_q_qt_1024(
    float v, int tid, int d, int q, int r,
    const float* __restrict__ g_sl, const float* __restrict__ b_sl,
    const float4* __restrict__ Wq4, const float* __restrict__ bq,
    const float4* __restrict__ Wkq4, const float* __restrict__ bk,
    float* __restrict__ qtbuf, float* __restrict__ qoffbuf,
    float* snorm, float* qrow, float* pq, float* redA, float* redB) {
    if (q == 0) { redA[d] = v; redB[d] = v * v; }
    float sm, s2;
    reduce256_in1024(redA, redB, tid, sm, s2);
    if (q == 0) {
        float m = sm * (1.f / C_);
        float rs = rsqrtf(s2 * (1.f / C_) - m * m + 1e-5f);
        snorm[d] = (v - m) * rs * g_sl[d] + b_sl[d];
    }
    __syncthreads();
    // q projection (quarter over c)
    {
        const float4* sn4 = (const float4*)snorm;
        float4 a0 = {0,0,0,0}, a1 = {0,0,0,0};
        int c4b = q << 4;
        #pragma unroll
        for (int i = 0; i < 16; i += 2) {
            fma4(a0, Wq4[(c4b + i) * 256 + d], sn4[c4b + i]);
            fma4(a1, Wq4[(c4b + i + 1) * 256 + d], sn4[c4b + i + 1]);
        }
        pq[q * 256 + d] = hsum4(a0) + hsum4(a1);
    }
    __syncthreads();
    if (q == 0) {
        float qfull = pq[d] + pq[256 + d] + pq[512 + d] + pq[768 + d] + bq[d];
        qrow[d] = qfull;
        redA[d] = qfull * bk[d]; redB[d] = 0.f;
    }
    float qoffv, dummy;
    reduce256_in1024(redA, redB, tid, qoffv, dummy);
    if (tid == 0) qoffbuf[r] = qoffv;
    // qt = q . Wk (quarter over d-rows of Wk)
    {
        const float4* q4 = (const float4*)qrow;
        float4 a0 = {0,0,0,0}, a1 = {0,0,0,0};
        int d4b = q << 4;
        #pragma unroll
        for (int i = 0; i < 16; i += 2) {
            fma4(a0, Wkq4[(d4b + i) * 256 + d], q4[d4b + i]);
            fma4(a1, Wkq4[(d4b + i + 1) * 256 + d], q4[d4b + i + 1]);
        }
        pq[q * 256 + d] = hsum4(a0) + hsum4(a1);
    }
    __syncthreads();
    if (q == 0)
        qtbuf[r * C_ + d] = pq[d] + pq[256 + d] + pq[512 + d] + pq[768 + d];
}

__global__ __launch_bounds__(1024) void slot_init_q_kernel(
    const float* __restrict__ noise, const float* __restrict__ mu,
    const float* __restrict__ log_sigma,
    const float* __restrict__ g_sl, const float* __restrict__ b_sl,
    const float4* __restrict__ Wq4, const float* __restrict__ bq,
    const float4* __restrict__ Wkq4, const float* __restrict__ bk,
    float* __restrict__ slots, float* __restrict__ qtbuf, float* __restrict__ qoffbuf) {
    __shared__ __align__(16) float snorm[256];
    __shared__ __align__(16) float qrow[256];
    __shared__ float pq[1024];
    __shared__ float redA[256], redB[256];
    int tid = threadIdx.x;
    int d = tid & 255, q = tid >> 8;
    int r = blockIdx.x;
    float v = 0.f;
    if (q == 0) {
        v = mu[d] + expf(log_sigma[d]) * noise[r * C_ + d];
        slots[r * C_ + d] = v;
    }
    ln_q_qt_1024(v, tid, d, q, r, g_sl, b_sl, Wq4, bq, Wkq4, bk,
                 qtbuf, qoffbuf, snorm, qrow, pq, redA, redB);
}

// slot update core; returns ov (valid for q==0 threads)
__device__ __forceinline__ float slot_update_body(
    int tid, int d, int q, int r, const float* __restrict__ slots,
    const float* __restrict__ partials, const float* __restrict__ asump,
    const float4* __restrict__ Wv4, const float* __restrict__ bv,
    const float4* __restrict__ Wu4, const float* __restrict__ bu,
    const float* __restrict__ g_mlp, const float* __restrict__ b_mlp,
    const float4* __restrict__ W14, const float* __restrict__ b1,
    const float4* __restrict__ W24, const float* __restrict__ b2,
    float* comb, float* pq, float* mrow, float* hrow,
    float* redA, float* redB, float* s_denom, float* s_scale) {
    int b = r >> 2, kk = r & 3;
    // phase 0: u'' partials reduce (16 chunks per quarter)
    {
        const float* pbase = partials + (size_t)b * 65536 + kk * 256 + d;
        float u0 = 0.f, u1 = 0.f, u2 = 0.f, u3 = 0.f;
        int j0 = q << 4;
        #pragma unroll
        for (int j = 0; j < 16; j += 4) {
            u0 += pbase[(j0 + j + 0) * 1024];
            u1 += pbase[(j0 + j + 1) * 1024];
            u2 += pbase[(j0 + j + 2) * 1024];
            u3 += pbase[(j0 + j + 3) * 1024];
        }
        pq[q * 256 + d] = (u0 + u1) + (u2 + u3);
    }
    if (tid < 64) {
        float dv = asump[(b * 64 + tid) * 4 + kk];
        #pragma unroll
        for (int m = 1; m <= 32; m <<= 1) dv += __shfl_xor(dv, m);
        if (tid == 0) { *s_denom = dv + EPS_; *s_scale = dv / (dv + EPS_); }
    }
    float prev = 0.f;
    if (q == 0) prev = slots[r * C_ + d];
    __syncthreads();
    if (q == 0) {
        comb[d] = prev;
        mrow[d] = (pq[d] + pq[256 + d] + pq[512 + d] + pq[768 + d]) / *s_denom;  // u'
    }
    __syncthreads();
    // phase V: updates = Wv . u' + s*bv  (quarter over e)
    {
        const float4* u4 = (const float4*)mrow;
        float4 a0 = {0,0,0,0}, a1 = {0,0,0,0};
        int e4b = q << 4;
        #pragma unroll
        for (int i = 0; i < 16; i += 2) {
            fma4(a0, Wv4[(e4b + i) * 256 + d], u4[e4b + i]);
            fma4(a1, Wv4[(e4b + i + 1) * 256 + d], u4[e4b + i + 1]);
        }
        pq[q * 256 + d] = hsum4(a0) + hsum4(a1);
    }
    __syncthreads();
    if (q == 0)
        comb[256 + d] = pq[d] + pq[256 + d] + pq[512 + d] + pq[768 + d] + *s_scale * bv[d];
    __syncthreads();
    // phase 1: Wu (K=512), quarter = 32 c4
    const float4* cb4 = (const float4*)comb;
    {
        float4 a0 = {0,0,0,0}, a1 = {0,0,0,0}, a2 = {0,0,0,0}, a3 = {0,0,0,0};
        int c4b = q << 5;
        #pragma unroll
        for (int i = 0; i < 32; i += 4) {
            float4 w0 = Wu4[(c4b + i + 0) * 256 + d];
            float4 w1 = Wu4[(c4b + i + 1) * 256 + d];
            float4 w2 = Wu4[(c4b + i + 2) * 256 + d];
            float4 w3 = Wu4[(c4b + i + 3) * 256 + d];
            fma4(a0, w0, cb4[c4b + i + 0]); fma4(a1, w1, cb4[c4b + i + 1]);
            fma4(a2, w2, cb4[c4b + i + 2]); fma4(a3, w3, cb4[c4b + i + 3]);
        }
        pq[q * 256 + d] = (hsum4(a0) + hsum4(a1)) + (hsum4(a2) + hsum4(a3));
    }
    __syncthreads();
    float nv = 0.f;
    if (q == 0) {
        nv = pq[d] + pq[256 + d] + pq[512 + d] + pq[768 + d] + bu[d] + prev;
        redA[d] = nv; redB[d] = nv * nv;
    }
    float sm, s2;
    reduce256_in1024(redA, redB, tid, sm, s2);
    if (q == 0) {
        float m = sm * (1.f / C_);
        float rs = rsqrtf(s2 * (1.f / C_) - m * m + 1e-5f);
        mrow[d] = (nv - m) * rs * g_mlp[d] + b_mlp[d];
    }
    __syncthreads();
    // phase 2: W1 (K=256 -> 512 outputs), halves (h2 = tid>>9)
    const float4* m4 = (const float4*)mrow;
    {
        int j = tid & 511, h2 = tid >> 9;
        float4 a0 = {0,0,0,0}, a1 = {0,0,0,0};
        int c4b = h2 << 5;
        #pragma unroll
        for (int i = 0; i < 32; i += 2) {
            float4 w0 = W14[(c4b + i + 0) * 512 + j];
            float4 w1 = W14[(c4b + i + 1) * 512 + j];
            fma4(a0, w0, m4[c4b + i + 0]); fma4(a1, w1, m4[c4b + i + 1]);
        }
        pq[h2 * 512 + j] = hsum4(a0) + hsum4(a1);
    }
    __syncthreads();
    if (tid < 512) hrow[tid] = gelu_f(pq[tid] + pq[512 + tid] + b1[tid]);
    __syncthreads();
    // phase 3: W2 (K=512)
    const float4* h4 = (const float4*)hrow;
    {
        float4 a0 = {0,0,0,0}, a1 = {0,0,0,0}, a2 = {0,0,0,0}, a3 = {0,0,0,0};
        int h4b = q << 5;
        #pragma unroll
        for (int i = 0; i < 32; i += 4) {
            float4 w0 = W24[(h4b + i + 0) * 256 + d];
            float4 w1 = W24[(h4b + i + 1) * 256 + d];
            float4 w2 = W24[(h4b + i + 2) * 256 + d];
            float4 w3 = W24[(h4b + i + 3) * 256 + d];
            fma4(a0, w0, h4[h4b + i + 0]); fma4(a1, w1, h4[h4b + i + 1]);
            fma4(a2, w2, h4[h4b + i + 2]); fma4(a3, w3, h4[h4b + i + 3]);
        }
        pq[q * 256 + d] = (hsum4(a0) + hsum4(a1)) + (hsum4(a2) + hsum4(a3));
    }
    __syncthreads();
    float ov = 0.f;
    if (q == 0)
        ov = nv + pq[d] + pq[256 + d] + pq[512 + d] + pq[768 + d] + b2[d];
    return ov;
}

__global__ __launch_bounds__(1024) void slot_update_q_kernel(
    float* __restrict__ slots, const float* __restrict__ partials, const float* __restrict__ asump,
    const float4* __restrict__ Wv4, const float* __restrict__ bv,
    const float4* __restrict__ Wu4, const float* __restrict__ bu,
    const float* __restrict__ g_mlp, const float* __restrict__ b_mlp,
    const float4* __restrict__ W14, const float* __restrict__ b1,
    const float4* __restrict__ W24, const float* __restrict__ b2,
    const float* __restrict__ g_sl, const float* __restrict__ b_sl,
    const float4* __restrict__ Wq4, const float* __restrict__ bq,
    const float4* __restrict__ Wkq4, const float* __restrict__ bk,
    float* __restrict__ qtbuf, float* __restrict__ qoffbuf) {
    __shared__ __align__(16) float comb[512];
    __shared__ __align__(16) float mrow[256];
    __shared__ __align__(16) float hrow[512];
    __shared__ float pq[1024];
    __shared__ float redA[256], redB[256];
    __shared__ float s_denom, s_scale;
    int tid = threadIdx.x;
    int d = tid & 255, q = tid >> 8;
    int r = blockIdx.x;
    float ov = slot_update_body(tid, d, q, r, slots, partials, asump, Wv4, bv, Wu4, bu,
                                g_mlp, b_mlp, W14, b1, W24, b2,
                                comb, pq, mrow, hrow, redA, redB, &s_denom, &s_scale);
    if (q == 0) slots[r * C_ + d] = ov;
    __syncthreads();
    ln_q_qt_1024(ov, tid, d, q, r, g_sl, b_sl, Wq4, bq, Wkq4, bk,
                 qtbuf, qoffbuf, mrow, comb, pq, redA, redB);
}

__global__ __launch_bounds__(1024) void slot_update_final_kernel(
    float* __restrict__ slots, const float* __restrict__ partials, const float* __restrict__ asump,
    const float4* __restrict__ Wv4, const float* __restrict__ bv,
    const float4* __restrict__ Wu4, const float* __restrict__ bu,
    const float* __restrict__ g_mlp, const float* __restrict__ b_mlp,
    const float4* __restrict__ W14, const float* __restrict__ b1,
    const float4* __restrict__ W24, const float* __restrict__ b2,
    const float4* __restrict__ We14, const float* __restrict__ be1,
    const float* __restrict__ We2, const float* __restrict__ be2,
    float* __restrict__ out) {
    __shared__ __align__(16) float comb[512];
    __shared__ __align__(16) float mrow[256];
    __shared__ __align__(16) float hrow[512];
    __shared__ float pq[1024];
    __shared__ float redA[256], redB[256];
    __shared__ float s_denom, s_scale;
    __shared__ float erow[128];
    int tid = threadIdx.x;
    int d = tid & 255, q = tid >> 8;
    int r = blockIdx.x;
    float ov = slot_update_body(tid, d, q, r, slots, partials, asump, Wv4, bv, Wu4, bu,
                                g_mlp, b_mlp, W14, b1, W24, b2,
                                comb, pq, mrow, hrow, redA, redB, &s_denom, &s_scale);
    if (q == 0) {
        out[r * C_ + d] = ov;
        mrow[d] = ov;
    }
    __syncthreads();
    // We1: 128 outputs, 8-way K split (o8 = tid>>7, 8 c4 each)
    const float4* m4 = (const float4*)mrow;
    {
        int e = tid & 127, o8 = tid >> 7;
        float4 a0 = {0,0,0,0}, a1 = {0,0,0,0};
        int c4b = o8 << 3;
        #pragma unroll
        for (int i = 0; i < 8; i += 2) {
            fma4(a0, We14[(c4b + i) * 128 + e], m4[c4b + i]);
            fma4(a1, We14[(c4b + i + 1) * 128 + e], m4[c4b + i + 1]);
        }
        pq[o8 * 128 + e] = hsum4(a0) + hsum4(a1);
    }
    __syncthreads();
    if (tid < 128) {
        float s = 0.f;
        #pragma unroll
        for (int o = 0; o < 8; ++o) s += pq[o * 128 + tid];
        erow[tid] = gelu_f(s + be1[tid]);
    }
    __syncthreads();
    if (tid < 64) {
        float p = We2[tid] * erow[tid] + We2[tid + 64] * erow[tid + 64];
        #pragma unroll
        for (int m = 1; m <= 32; m <<= 1) p += __shfl_xor(p, m);
        if (tid == 0) out[B_ * K_ * C_ + r] = 1.0f / (1.0f + expf(-(p + be2[0])));
    }
}

// ---------------- fused attention: reads xnb directly (no k/v materialized) ----------------
// logits = qt.xn + qoff; u'' = sum_n attn * xn  (phase B re-reads L2-hot lines)
__global__ __launch_bounds__(256) void attn_fused_kernel(
    const float* __restrict__ qtbuf, const float* __restrict__ qoffbuf,
    const unsigned short* __restrict__ xnb,
    float* __restrict__ partials, float* __restrict__ asump) {
    __shared__ float4 qT[264];
    __shared__ float attns[K_][64];
    __shared__ float upd_s[K_][256];
    __shared__ float asw[4][4];
    __shared__ float4 qo_s;

    const int tid = threadIdx.x;
    const int b = blockIdx.y;
    const int chunk = blockIdx.x;
    const int n0 = chunk << 6;
    const int wave = tid >> 6, lane = tid & 63;

    {
        int c = tid;
        float4 qv;
        qv.x = qtbuf[b * 1024 + c];
        qv.y = qtbuf[b * 1024 + 256 + c];
        qv.z = qtbuf[b * 1024 + 512 + c];
        qv.w = qtbuf[b * 1024 + 768 + c];
        qT[c + (c >> 5)] = qv;
        if (tid == 0) qo_s = *(const float4*)&qoffbuf[b * 4];
    }
    __syncthreads();

    const int cpart = tid & 7;
    const int npair = tid >> 3;
    const int c0 = cpart << 5;
    float4 acc0 = {0.f, 0.f, 0.f, 0.f}, acc1 = {0.f, 0.f, 0.f, 0.f};
    const unsigned short* kbase = xnb + ((size_t)b * NPIX + n0 + npair * 2) * C_ + c0;
    #pragma unroll
    for (int j = 0; j < 4; ++j) {
        uint4 k0 = *reinterpret_cast<const uint4*>(kbase + j * 8);
        uint4 k1 = *reinterpret_cast<const uint4*>(kbase + C_ + j * 8);
        const unsigned kw0[4] = {k0.x, k0.y, k0.z, k0.w};
        const unsigned kw1[4] = {k1.x, k1.y, k1.z, k1.w};
        #pragma unroll
        for (int jj = 0; jj < 4; ++jj) {
            int cidx = c0 + j * 8 + jj * 2 + cpart;
            float4 qa = qT[cidx];
            float4 qb = qT[cidx + 1];
            float f00 = bflo(kw0[jj]), f01 = bfhi(kw0[jj]);
            float f10 = bflo(kw1[jj]), f11 = bfhi(kw1[jj]);
            acc0.x += f00 * qa.x + f01 * qb.x;  acc0.y += f00 * qa.y + f01 * qb.y;
            acc0.z += f00 * qa.z + f01 * qb.z;  acc0.w += f00 * qa.w + f01 * qb.w;
            acc1.x += f10 * qa.x + f11 * qb.x;  acc1.y += f10 * qa.y + f11 * qb.y;
            acc1.z += f10 * qa.z + f11 * qb.z;  acc1.w += f10 * qa.w + f11 * qb.w;
        }
    }
    #pragma unroll
    for (int m = 1; m <= 4; m <<= 1) {
        acc0 = acc0 + shfl_xor4(acc0, m);
        acc1 = acc1 + shfl_xor4(acc1, m);
    }
    float4 w0, w1;
    {
        float4 l = (acc0 + qo_s) * 0.0625f;
        float mx = fmaxf(fmaxf(l.x, l.y), fmaxf(l.z, l.w));
        w0.x = expf(l.x - mx); w0.y = expf(l.y - mx);
        w0.z = expf(l.z - mx); w0.w = expf(l.w - mx);
        float inv = 1.0f / (w0.x + w0.y + w0.z + w0.w);
        w0 = w0 * inv;
        l = (acc1 + qo_s) * 0.0625f;
        mx = fmaxf(fmaxf(l.x, l.y), fmaxf(l.z, l.w));
        w1.x = expf(l.x - mx); w1.y = expf(l.y - mx);
        w1.z = expf(l.z - mx); w1.w = expf(l.w - mx);
        inv = 1.0f / (w1.x + w1.y + w1.z + w1.w);
        w1 = w1 * inv;
    }
    if (cpart == 0) {
        int n_l = npair * 2;
        attns[0][n_l] = w0.x; attns[1][n_l] = w0.y; attns[2][n_l] = w0.z; attns[3][n_l] = w0.w;
        attns[0][n_l + 1] = w1.x; attns[1][n_l + 1] = w1.y;
        attns[2][n_l + 1] = w1.z; attns[3][n_l + 1] = w1.w;
    }
    float4 ws = w0 + w1;
    #pragma unroll
    for (int m = 8; m <= 32; m <<= 1) ws = ws + shfl_xor4(ws, m);
    if (lane == 0) {
        asw[wave][0] = ws.x; asw[wave][1] = ws.y; asw[wave][2] = ws.z; asw[wave][3] = ws.w;
    }
    __syncthreads();
    if (tid < 4)
        asump[(b * 64 + chunk) * 4 + tid] =
            asw[0][tid] + asw[1][tid] + asw[2][tid] + asw[3][tid];

    const int h = wave >> 1;
    const int chalf = (wave & 1) << 7;
    const int c = chalf + lane * 2;
    float a0[K_] = {0.f, 0.f, 0.f, 0.f};
    float a1[K_] = {0.f, 0.f, 0.f, 0.f};
    const unsigned short* vbase = xnb + ((size_t)b * NPIX + n0 + h * 32) * C_ + c;
    #pragma unroll 4
    for (int nn = 0; nn < 32; ++nn) {
        unsigned vv = *reinterpret_cast<const unsigned*>(vbase + (size_t)nn * C_);
        float v0 = bflo(vv), v1 = bfhi(vv);
        int n_l = h * 32 + nn;
        float q0 = attns[0][n_l], q1 = attns[1][n_l], q2 = attns[2][n_l], q3 = attns[3][n_l];
        a0[0] = fmaf(q0, v0, a0[0]); a1[0] = fmaf(q0, v1, a1[0]);
        a0[1] = fmaf(q1, v0, a0[1]); a1[1] = fmaf(q1, v1, a1[1]);
        a0[2] = fmaf(q2, v0, a0[2]); a1[2] = fmaf(q2, v1, a1[2]);
        a0[3] = fmaf(q3, v0, a0[3]); a1[3] = fmaf(q3, v1, a1[3]);
    }
    __syncthreads();
    if (h == 0) {
        #pragma unroll
        for (int k = 0; k < K_; ++k) { upd_s[k][c] = a0[k]; upd_s[k][c + 1] = a1[k]; }
    }
    __syncthreads();
    if (h == 1) {
        #pragma unroll
        for (int k = 0; k < K_; ++k) { upd_s[k][c] += a0[k]; upd_s[k][c + 1] += a1[k]; }
    }
    __syncthreads();
    float* pb = partials + (size_t)(b * 64 + chunk) * (K_ * 256);
    #pragma unroll
    for (int k = 0; k < K_; ++k) pb[k * 256 + tid] = upd_s[k][tid];
}

extern "C" void kernel_launch(void* const* d_in, const int* in_sizes, int n_in,
                              void* d_out, int out_size, void* d_ws, size_t ws_size,
                              hipStream_t stream) {
    (void)in_sizes; (void)n_in; (void)out_size; (void)ws_size;
    const float* x        = (const float*)d_in[0];
    const float* noise    = (const float*)d_in[1];
    const float* slot_mu  = (const float*)d_in[2];
    const float* slot_ls  = (const float*)d_in[3];
    const float* ln_in_g  = (const float*)d_in[4];
    const float* ln_in_b  = (const float*)d_in[5];
    const float* ln_sl_g  = (const float*)d_in[6];
    const float* ln_sl_b  = (const float*)d_in[7];
    const float* ln_mlp_g = (const float*)d_in[8];
    const float* ln_mlp_b = (const float*)d_in[9];
    const float* Wq = (const float*)d_in[10];
    const float* bq = (const float*)d_in[11];
    const float* Wk = (const float*)d_in[12];
    const float* bk = (const float*)d_in[13];
    const float* Wv = (const float*)d_in[14];
    const float* bv = (const float*)d_in[15];
    const float* Wu = (const float*)d_in[16];
    const float* bu = (const float*)d_in[17];
    const float* W1 = (const float*)d_in[18];
    const float* b1 = (const float*)d_in[19];
    const float* W2 = (const float*)d_in[20];
    const float* b2 = (const float*)d_in[21];
    const float* We1 = (const float*)d_in[22];
    const float* be1 = (const float*)d_in[23];
    const float* We2 = (const float*)d_in[24];
    const float* be2 = (const float*)d_in[25];
    float* out = (float*)d_out;

    char* ws = (char*)d_ws;
    unsigned short* xnb = (unsigned short*)ws;                  // 32 MiB
    float4* Wq4  = (float4*)(xnb + (size_t)NROWS * C_);
    float4* Wu4  = Wq4 + 16384;
    float4* W14  = Wu4 + 32768;
    float4* W24  = W14 + 32768;
    float4* We14 = W24 + 32768;
    float4* Wkq4 = We14 + 8192;
    float4* Wv4  = Wkq4 + 16384;
    float* slots = (float*)(Wv4 + 16384);
    float* qtbuf = slots + B_ * K_ * C_;
    float* qoffb = qtbuf + B_ * K_ * C_;
    float* partials = qoffb + B_ * K_;
    float* asump = partials + (size_t)B_ * 64 * K_ * 256;

    prep_kernel<<<608, 256, 0, stream>>>(Wq, Wu, W1, W2, We1, Wk, Wv,
                                         Wq4, Wu4, W14, W24, We14, Wkq4, Wv4);
    xn_fused_kernel<<<dim3(64, 16), 256, 0, stream>>>(x, ln_in_g, ln_in_b, xnb);
    slot_init_q_kernel<<<B_ * K_, 1024, 0, stream>>>(noise, slot_mu, slot_ls,
                                                     ln_sl_g, ln_sl_b, Wq4, bq, Wkq4, bk,
                                                     slots, qtbuf, qoffb);
    for (int it = 0; it < ITERS_; ++it) {
        attn_fused_kernel<<<dim3(64, 16), 256, 0, stream>>>(qtbuf, qoffb, xnb,
                                                            partials, asump);
        if (it < ITERS_ - 1) {
            slot_update_q_kernel<<<B_ * K_, 1024, 0, stream>>>(
                slots, partials, asump, Wv4, bv, Wu4, bu, ln_mlp_g, ln_mlp_b,
                W14, b1, W24, b2, ln_sl_g, ln_sl_b, Wq4, bq, Wkq4, bk, qtbuf, qoffb);
        } else {
            slot_update_final_kernel<<<B_ * K_, 1024, 0, stream>>>(
                slots, partials, asump, Wv4, bv, Wu4, bu, ln_mlp_g, ln_mlp_b,
                W14, b1, W24, b2, We14, be1, We2, be2, out);
        }
    }
}